// Round 17
// baseline (153.223 us; speedup 1.0000x reference)
//
#include <hip/hip_runtime.h>

// Guided filter r=8 (K=17), eps=0.1, (8,3,1024,1024); f32 in / f32 out.
// V9 = R16 + quad-interleaved LDS arena: one [48 rows][65 float4] region
// (49,920 B, 3 blocks/CU; pad col -> stride 65 = bank-balanced for every
// access pattern). A writes (s0,s1,s2,s3) as b128; C reads (hsA,hsB) as b64.
// LDS instr/thread 144 -> 82. B1 keeps only the slide window (88 regs) to
// stay under the 128-VGPR occupancy step.
//
//   A : vertical 17-tap sliding sums {I,p,Ip,II} (28-row reg window)
//       -> quad per (row,col), 12 ds_write_b128
//   B1: horizontal 17-sums of quads (28 b128 reads) -> a,b via rcp-folded
//       form; write (a,b) pairs over f4 cols 0..23
//   B2: horizontal 17-sums of (a,b) (12 b128) -> (hsA,hsB) pairs, f4 cols 40..55
//   C : vertical 17-sums of hs pairs (20 b64) + out = INV*fma(sa,I,sb)

#define TW 32
#define TH 32
#define AR 48
#define F4STR 65                   // float4 per row (1040 B row stride)
#define INV_AREA (1.0f / 289.0f)

__device__ __forceinline__ int refl1024(int v) {
    v = (v < 0) ? -v : v;
    v = (v > 1023) ? 2046 - v : v;
    if (v < 0) v = 0;
    if (v > 1023) v = 1023;
    return v;
}

__global__ __launch_bounds__(256) void gf_fused(
    const float* __restrict__ P, const float* __restrict__ I,
    float* __restrict__ O, int H, int W)
{
    __shared__ __align__(16) float4 S4[AR * F4STR];   // 49920 B
    float2* __restrict__ Sf2 = (float2*)S4;

    const int tid = threadIdx.x;
    const int tx0 = blockIdx.x * TW;
    const int ty0 = blockIdx.y * TH;
    const size_t plane = (size_t)blockIdx.z * H * W;
    const float* __restrict__ Ic = I + plane;
    const float* __restrict__ Pc = P + plane;

    // ---------------- Phase A: vertical sliding sums -> quads ---------------
    {
        const int vc = tid & 63;                                   // vs col
        const int ck = __builtin_amdgcn_readfirstlane(tid >> 6);   // wave-uniform
        const int r0 = ck * 12;
        const int gx = refl1024(tx0 + vc - 16);

        float vI[28], vP[28];
        #pragma unroll
        for (int j = 0; j < 28; ++j) {
            const int gy = refl1024(ty0 + r0 - 16 + j);            // scalar
            const float* __restrict__ rI = Ic + (size_t)gy * W;    // SGPR base
            const float* __restrict__ rP = Pc + (size_t)gy * W;
            vI[j] = rI[gx];
            vP[j] = rP[gx];
        }
        float s0 = 0.f, s1 = 0.f, s2 = 0.f, s3 = 0.f;
        #pragma unroll
        for (int j = 0; j < 17; ++j) {
            s0 += vI[j]; s1 += vP[j];
            s2 += vI[j] * vP[j];
            s3 += vI[j] * vI[j];
        }
        S4[r0 * F4STR + vc] = make_float4(s0, s1, s2, s3);
        #pragma unroll
        for (int o = 1; o < 12; ++o) {
            const float ni = vI[o + 16], oi = vI[o - 1];
            const float np_ = vP[o + 16], op_ = vP[o - 1];
            s0 += ni - oi;
            s1 += np_ - op_;
            s2 += ni * np_ - oi * op_;
            s3 += ni * ni - oi * oi;
            S4[(r0 + o) * F4STR + vc] = make_float4(s0, s1, s2, s3);
        }
    }
    __syncthreads();

    // ---------------- Phase B1: horizontal sums -> a,b ----------------------
    const int vr = (tid & 15) + ((tid >> 6) << 4);   // 0..47 (tid<192)
    const int u4 = (tid >> 4) & 3;                   // col-block (12 ab cols)
    float oa[12], ob[12];
    if (tid < 192) {
        // keep only slide window: j in [0,10] (drop side) and [17,27] (add side)
        float k0l[11], k1l[11], k2l[11], k3l[11];
        float k0h[11], k1h[11], k2h[11], k3h[11];
        float s0 = 0.f, s1 = 0.f, s2 = 0.f, s3 = 0.f;
        #pragma unroll
        for (int j = 0; j < 28; ++j) {
            const float4 w = S4[vr * F4STR + u4 * 12 + j];
            if (j < 17) { s0 += w.x; s1 += w.y; s2 += w.z; s3 += w.w; }
            if (j < 11) { k0l[j] = w.x; k1l[j] = w.y; k2l[j] = w.z; k3l[j] = w.w; }
            if (j >= 17) {
                const int m = j - 17;
                k0h[m] = w.x; k1h[m] = w.y; k2h[m] = w.z; k3h[m] = w.w;
            }
        }
        #pragma unroll
        for (int o = 0; o < 12; ++o) {
            if (o) {
                s0 += k0h[o - 1] - k0l[o - 1];
                s1 += k1h[o - 1] - k1l[o - 1];
                s2 += k2h[o - 1] - k2l[o - 1];
                s3 += k3h[o - 1] - k3l[o - 1];
            }
            const float num = fmaf(289.0f, s2, -s0 * s1);
            const float den = fmaf(289.0f, s3, -s0 * s0) + 8352.1f; // 289^2*0.1
            const float av  = num * __builtin_amdgcn_rcpf(den);
            oa[o] = av;
            ob[o] = fmaf(-av, s0, s1) * INV_AREA;
        }
    }
    __syncthreads();
    if (tid < 192) {
        // (a,b) pairs over f4 cols 0..23: col pair (2t,2t+1) of this block
        #pragma unroll
        for (int t = 0; t < 6; ++t)
            S4[vr * F4STR + u4 * 6 + t] =
                make_float4(oa[2 * t], ob[2 * t], oa[2 * t + 1], ob[2 * t + 1]);
    }
    __syncthreads();

    // ---------------- Phase B2: horizontal sums of (a,b) -> hs pairs --------
    if (tid < 192) {
        float qa[24], qb[24];
        #pragma unroll
        for (int t = 0; t < 12; ++t) {
            const float4 w = S4[vr * F4STR + u4 * 4 + t];
            qa[2 * t] = w.x;     qb[2 * t] = w.y;
            qa[2 * t + 1] = w.z; qb[2 * t + 1] = w.w;
        }
        float hsA[8], hsB[8];
        float sa = 0.f, sb = 0.f;
        #pragma unroll
        for (int j = 0; j < 17; ++j) { sa += qa[j]; sb += qb[j]; }
        hsA[0] = sa; hsB[0] = sb;
        #pragma unroll
        for (int o = 1; o < 8; ++o) {
            sa += qa[o + 16] - qa[o - 1];
            sb += qb[o + 16] - qb[o - 1];
            hsA[o] = sa; hsB[o] = sb;
        }
        // (hsA,hsB) pairs at f4 cols 40..55 (disjoint from ab cols 0..23)
        #pragma unroll
        for (int t = 0; t < 4; ++t)
            S4[vr * F4STR + 40 + u4 * 4 + t] =
                make_float4(hsA[2 * t], hsB[2 * t], hsA[2 * t + 1], hsB[2 * t + 1]);
    }
    __syncthreads();

    // ---------------- Phase C: vertical sums + finale -----------------------
    {
        const int ox  = tid & 31;
        const int oy0 = (tid >> 5) * 4;    // 0,4,...,28
        float ca[20], cb[20];
        #pragma unroll
        for (int j = 0; j < 20; ++j) {
            const float2 w = Sf2[(oy0 + j) * (F4STR * 2) + 80 + ox];
            ca[j] = w.x; cb[j] = w.y;
        }
        float sa = 0.f, sb = 0.f;
        #pragma unroll
        for (int j = 0; j < 17; ++j) { sa += ca[j]; sb += cb[j]; }
        #pragma unroll
        for (int o = 0; o < 4; ++o) {
            if (o) {
                sa += ca[o + 16] - ca[o - 1];
                sb += cb[o + 16] - cb[o - 1];
            }
            const size_t gp = (size_t)(ty0 + oy0 + o) * W + (tx0 + ox);
            O[plane + gp] = INV_AREA * fmaf(sa, Ic[gp], sb);
        }
    }
}

extern "C" void kernel_launch(void* const* d_in, const int* in_sizes, int n_in,
                              void* d_out, int out_size, void* d_ws, size_t ws_size,
                              hipStream_t stream) {
    const int H = 1024, W = 1024;
    if (n_in < 2) return;
    const long long npx = (long long)H * W;
    const long long n0 = in_sizes[0];
    if (n0 <= 0 || (n0 % npx) != 0) return;
    if ((long long)out_size != n0) return;
    if (in_sizes[1] != in_sizes[0]) return;
    const int NP = (int)(n0 / npx);

    const float* p = (const float*)d_in[0];   // input_img
    const float* I = (const float*)d_in[1];   // guide_img
    float* out = (float*)d_out;

    dim3 grid(W / TW, H / TH, NP);
    gf_fused<<<grid, 256, 0, stream>>>(p, I, out, H, W);
}